// Round 7
// baseline (80.552 us; speedup 1.0000x reference)
//
#include <hip/hip_runtime.h>
#include <stdint.h>

// AdderNet 2D: out[n,f,i,j] = -sum_{c,ki,kj} |W[f,c,ki,kj] - xpad[n,c,i+ki,j+kj]|
// x: [8,64,32,32] f32, W: [64,64,3,3] f32, out: [8,64,32,32] f32
//
// R7: |w-x| = (w+x) - 2*min(w,x) => out = 2*Sum(min) - SW_f - Sx_window.
// fp16 channel-paired: v_pk_min_f16 + v_dot2_f32_f16 = 1 instr/term, fp32
// accumulation. R6 left ~20% VALU efficiency; suspect = s_load weights in
// the hot loop (out-of-order SMEM forces lgkmcnt(0), draining ds_reads).
// Fix: weights in LDS packed per-(ch2,k) as uint4 (4 filters) -> 9 broadcast
// ds_read_b128 per cc-pair; hot loop is now DS-only (in-order, fine-grained
// lgkmcnt). Block 512T = 8 waves = 8 channel slices of one (n, 4-filter
// group, 16x16 quarter); LDS combine; coalesced float4 stores. No atomics.

typedef _Float16 half2v __attribute__((ext_vector_type(2)));

#define XS   20                 // u32 stride per LDS row (2-way bank alias = free)
#define RH   18                 // rows incl. halo
#define CH2  32                 // channel pairs
#define XCHW (RH * XS)          // 360 u32 per channel-pair
#define W2_U32 (CH2 * 16 * 9 * 4)       // 18432 u32
#define WS_NEEDED (W2_U32 * 4 + 64 * 4)

// ---- pre-kernel: pack W fp16 pairs as uint4[(ch2*16+fg)*9+k] = {f0,f1,f2,f3}
__global__ __launch_bounds__(64)
void prep_kernel(const float* __restrict__ W, uint32_t* __restrict__ W2,
                 float* __restrict__ SW) {
    const int f    = blockIdx.x;     // 0..63
    const int lane = threadIdx.x;    // 0..63
    float s = 0.0f;
    for (int i = lane; i < CH2 * 9; i += 64) {
        const int ch2 = i / 9;
        const int k   = i - ch2 * 9;
        const float a = W[(size_t)f * 576 + (2 * ch2) * 9 + k];
        const float b = W[(size_t)f * 576 + (2 * ch2 + 1) * 9 + k];
        const _Float16 ha = (_Float16)a;   // RNE
        const _Float16 hb = (_Float16)b;
        const uint16_t ua = __builtin_bit_cast(uint16_t, ha);
        const uint16_t ub = __builtin_bit_cast(uint16_t, hb);
        W2[((((size_t)ch2 * 16 + (f >> 2)) * 9 + k) << 2) + (f & 3)] =
            (uint32_t)ua | ((uint32_t)ub << 16);
        s += (float)ha + (float)hb;
    }
#pragma unroll
    for (int m = 32; m >= 1; m >>= 1) s += __shfl_xor(s, m, 64);
    if (lane == 0) SW[f] = s;
}

// ---------------------------- main kernel ----------------------------------
__global__ __launch_bounds__(512, 2)
void adder2d_kernel(const float* __restrict__ x,
                    const uint4* __restrict__ W2,
                    const float* __restrict__ SW,
                    float* __restrict__ out) {
    __shared__ uint32_t xs[CH2 * XCHW];   // 46080 B (reused for partials)
    __shared__ uint4 wl[CH2 * 9];         //  4608 B

    const int bid     = blockIdx.x;
    const int quarter = bid & 3;
    const int fg      = (bid >> 2) & 15;
    const int n       = bid >> 6;
    const int r0      = (quarter >> 1) * 16;
    const int c0      = (quarter & 1) * 16;
    const int tid     = threadIdx.x;

    // ---- stage weights for this filter group into LDS ----
    for (int idx = tid; idx < CH2 * 9; idx += 512) {
        const int ch2 = idx / 9;
        const int k   = idx - 9 * ch2;
        wl[idx] = W2[((size_t)ch2 * 16 + fg) * 9 + k];
    }

    // ---- stage x quarter (+halo) as fp16 channel-pairs ----
    {
        const int ch2s = tid >> 4;
        const int sub  = tid & 15;
        const float* xa = x + ((size_t)n * 64 + 2 * ch2s) * 1024;
        for (int cell = sub; cell < RH * RH; cell += 16) {
            const int row = cell / RH;
            const int col = cell - row * RH;
            const int ir  = r0 + row - 1;
            const int ic  = c0 + col - 1;
            float a = 0.0f, b = 0.0f;
            if ((unsigned)ir < 32u && (unsigned)ic < 32u) {
                a = xa[ir * 32 + ic];
                b = xa[1024 + ir * 32 + ic];
            }
            const _Float16 ha = (_Float16)a;     // RNE
            const _Float16 hb = (_Float16)b;
            xs[ch2s * XCHW + row * XS + col] =
                (uint32_t)__builtin_bit_cast(uint16_t, ha) |
                ((uint32_t)__builtin_bit_cast(uint16_t, hb) << 16);
        }
    }
    __syncthreads();

    const int wave = __builtin_amdgcn_readfirstlane(tid >> 6);  // SGPR-uniform
    const int lane = tid & 63;
    const int tx   = lane & 7;        // px cols 2tx, 2tx+1
    const int ty   = lane >> 3;       // px rows 2ty, 2ty+1

    const half2v one2 = {(_Float16)1.0f, (_Float16)1.0f};
    float acc[16];                    // [f][sub]  sub = sr*2+sc
    float sx[4];
#pragma unroll
    for (int i = 0; i < 16; ++i) acc[i] = 0.0f;
#pragma unroll
    for (int i = 0; i < 4; ++i) sx[i] = 0.0f;

#pragma unroll
    for (int i = 0; i < 4; ++i) {
        const int ch2 = wave * 4 + i;

        // 4x4 window of channel-pairs (8B-aligned ds_read_b64 pairs)
        uint32_t xw[4][4];
#pragma unroll
        for (int r = 0; r < 4; ++r) {
            const uint32_t* p = &xs[ch2 * XCHW + (2 * ty + r) * XS + 2 * tx];
            const uint2 A = *(const uint2*)p;
            const uint2 B = *(const uint2*)(p + 2);
            xw[r][0] = A.x; xw[r][1] = A.y; xw[r][2] = B.x; xw[r][3] = B.y;
        }

#pragma unroll
        for (int k = 0; k < 9; ++k) {
            const int ki = k / 3, kj = k - 3 * ki;
            const uint4 wk = wl[ch2 * 9 + k];    // broadcast ds_read_b128
            const uint32_t wf_[4] = {wk.x, wk.y, wk.z, wk.w};
#pragma unroll
            for (int sr = 0; sr < 2; ++sr)
#pragma unroll
                for (int sc = 0; sc < 2; ++sc) {
                    const half2v xv =
                        __builtin_bit_cast(half2v, xw[sr + ki][sc + kj]);
                    const int sub = sr * 2 + sc;
                    sx[sub] = __builtin_amdgcn_fdot2(xv, one2, sx[sub], false);
#pragma unroll
                    for (int f = 0; f < 4; ++f) {
                        const half2v w2 = __builtin_bit_cast(half2v, wf_[f]);
                        const half2v m  = __builtin_elementwise_min(w2, xv);
                        acc[f * 4 + sub] =
                            __builtin_amdgcn_fdot2(m, one2, acc[f * 4 + sub], false);
                    }
                }
        }
    }

    // ---- combine the 8 channel-slice waves via LDS ----
    __syncthreads();                       // all xs/wl reads done
    float* ps = (float*)xs;                // [8 waves][64 lanes][20 slots]
#pragma unroll
    for (int s = 0; s < 16; ++s) ps[((wave * 64 + lane) * 20) + s] = acc[s];
#pragma unroll
    for (int s = 0; s < 4; ++s) ps[((wave * 64 + lane) * 20) + 16 + s] = sx[s];
    __syncthreads();

    // ---- reduce + store: 2 outputs/thread (same px, 2 filters) ----
    const int px  = tid & 255;
    const int fp  = tid >> 8;              // 0..1
    const int row = px >> 4, col = px & 15;
    const int lane_s = (row >> 1) * 8 + (col >> 1);
    const int sub_s  = (row & 1) * 2 + (col & 1);

    float sxs = 0.0f;
#pragma unroll
    for (int w = 0; w < 8; ++w)
        sxs += ps[(w * 64 + lane_s) * 20 + 16 + sub_s];
#pragma unroll
    for (int f2 = 0; f2 < 2; ++f2) {
        const int f = fp * 2 + f2;
        float m = 0.0f;
#pragma unroll
        for (int w = 0; w < 8; ++w)
            m += ps[(w * 64 + lane_s) * 20 + f * 4 + sub_s];
        const float val = 2.0f * m - SW[fg * 4 + f] - sxs;
        out[(((size_t)n * 64 + fg * 4 + f) * 32 + r0 + row) * 32 + c0 + col] = val;
    }
}

// ------------------- fallback (R2 structure, fp32, proven) -----------------
#define FB_CCHUNK 16
#define FB_XROW 36
#define FB_XCH (10 * FB_XROW)
#define FB_WPAD 12
__global__ __launch_bounds__(256, 6)
void adder2d_fb(const float* __restrict__ x, const float* __restrict__ Wt,
                float* __restrict__ out) {
    __shared__ float fxs[FB_CCHUNK * FB_XCH];
    __shared__ float fws[4 * FB_CCHUNK * FB_WPAD];
    const int bid = blockIdx.x;
    const int ks = bid & 3, fg = (bid >> 2) & 15, tile = (bid >> 6) & 3, n = bid >> 8;
    const int c0 = ks * FB_CCHUNK, f0 = fg * 4, i0 = tile * 8, tid = threadIdx.x;
    for (int idx = tid; idx < 4 * FB_CCHUNK * 9; idx += 256) {
        const int f = idx / (FB_CCHUNK * 9), rem = idx - f * (FB_CCHUNK * 9);
        const int cc = rem / 9, kk = rem - cc * 9;
        fws[(f * FB_CCHUNK + cc) * FB_WPAD + kk] =
            Wt[((size_t)(f0 + f) * 64 + (c0 + cc)) * 9 + kk];
    }
    const float* xn = x + ((size_t)n * 64 + c0) * 1024;
    for (int idx = tid; idx < FB_CCHUNK * FB_XCH; idx += 256) {
        const int cc = idx / FB_XCH, rem = idx - cc * FB_XCH;
        const int row = rem / FB_XROW, col = rem - row * FB_XROW;
        const int ir = i0 + row - 1, ic = col - 1;
        float v = 0.0f;
        if ((unsigned)ir < 32u && (unsigned)ic < 32u) v = xn[cc * 1024 + ir * 32 + ic];
        fxs[idx] = v;
    }
    __syncthreads();
    const int r = tid >> 5, j = tid & 31;
    float acc[4] = {0, 0, 0, 0};
#pragma unroll 2
    for (int cc = 0; cc < FB_CCHUNK; ++cc) {
        const float* xp = &fxs[cc * FB_XCH + r * FB_XROW + j];
        const float x00 = xp[0], x01 = xp[1], x02 = xp[2];
        const float x10 = xp[36], x11 = xp[37], x12 = xp[38];
        const float x20 = xp[72], x21 = xp[73], x22 = xp[74];
#pragma unroll
        for (int f = 0; f < 4; ++f) {
            const float* wq = &fws[(f * FB_CCHUNK + cc) * FB_WPAD];
            acc[f] += fabsf(wq[0] - x00) + fabsf(wq[1] - x01) + fabsf(wq[2] - x02)
                    + fabsf(wq[3] - x10) + fabsf(wq[4] - x11) + fabsf(wq[5] - x12)
                    + fabsf(wq[6] - x20) + fabsf(wq[7] - x21) + fabsf(wq[8] - x22);
        }
    }
    const int irow = i0 + r;
#pragma unroll
    for (int f = 0; f < 4; ++f)
        atomicAdd(&out[(((size_t)n * 64 + (f0 + f)) * 32 + irow) * 32 + j], -acc[f]);
}

extern "C" void kernel_launch(void* const* d_in, const int* in_sizes, int n_in,
                              void* d_out, int out_size, void* d_ws, size_t ws_size,
                              hipStream_t stream) {
    const float* x  = (const float*)d_in[0];
    const float* W  = (const float*)d_in[1];
    float* out      = (float*)d_out;

    if (ws_size >= (size_t)WS_NEEDED) {
        uint32_t* W2 = (uint32_t*)d_ws;
        float* SW    = (float*)((char*)d_ws + (size_t)W2_U32 * 4);
        hipLaunchKernelGGL(prep_kernel, dim3(64), dim3(64), 0, stream, W, W2, SW);
        hipLaunchKernelGGL(adder2d_kernel, dim3(512), dim3(512), 0, stream,
                           x, (const uint4*)W2, SW, out);
    } else {
        hipMemsetAsync(d_out, 0, (size_t)out_size * sizeof(float), stream);
        hipLaunchKernelGGL(adder2d_fb, dim3(2048), dim3(256), 0, stream, x, W, out);
    }
}